// Round 22
// baseline (959.407 us; speedup 1.0000x reference)
//
#include <hip/hip_runtime.h>
#include <hip/hip_bf16.h>
#include <stdint.h>

typedef __attribute__((ext_vector_type(4))) float f32x4;
typedef __attribute__((ext_vector_type(8))) __bf16 bf16x8;
typedef __attribute__((ext_vector_type(4))) unsigned short u16x4;
typedef __attribute__((ext_vector_type(8))) unsigned short u16x8;
typedef unsigned short u16;

#define NTOK 8192
#define DDIM 1024
#define FDIM 4096
#define NEXP 8
#define NT1 144

// ---- workspace layout (bytes) ----
#define WS_XB    0ull
#define WS_W1T   (16777216ull)                 // w1t for gemm1; REUSED as y[rows][1024] bf16 by gemm2
#define WS_W2T   (WS_W1T + 134217728ull)
#define WS_ACT   (WS_W2T + 67108864ull)
#define WS_LIST  (WS_ACT + 142606336ull)
#define WS_PAIRW (WS_LIST + 262144ull)
#define WS_CNT   (WS_PAIRW + 262144ull)
#define WS_SUMP  (WS_CNT + 32ull)
#define WS_PAD   (WS_SUMP + 32ull)
#define WS_OFF   (WS_PAD + 32ull)
#define WS_T1E   (WS_OFF + 32ull)              // 144 int (1 KiB reserved)
#define WS_T1R   (WS_T1E + 1024ull)            // 144 int (1 KiB reserved)
#define WS_SE    (WS_T1R + 1024ull)            // 8192*2 int
#define WS_SP    (WS_SE + 65536ull)            // 8192*2 int

static __device__ __forceinline__ u16 bf16rne(float f) {
  union { float f; uint32_t u; } c; c.f = f;
  return (u16)((c.u + 0x7FFFu + ((c.u >> 16) & 1u)) >> 16);
}

static __device__ __forceinline__ float bf16tof(u16 v) {
  union { uint32_t u; float f; } c; c.u = ((uint32_t)v) << 16;
  return c.f;
}

static __device__ __forceinline__ void load_lds16(const void* g, void* l) {
  __builtin_amdgcn_global_load_lds((const __attribute__((address_space(1))) void*)g,
                                   (__attribute__((address_space(3))) void*)l, 16, 0, 0);
}

// ---------------- gating + routing + x->bf16 ----------------
__global__ __launch_bounds__(256) void gate_kernel(
    const float* __restrict__ x, const float* __restrict__ gw,
    const float* __restrict__ gb, u16* __restrict__ xb,
    int* __restrict__ cnt, float* __restrict__ sump,
    int* __restrict__ list, float* __restrict__ pairw,
    int* __restrict__ slotE, int* __restrict__ slotP) {
  const int tid = threadIdx.x;
  const int lane = tid & 63;
  const int wv = tid >> 6;
  const int t = blockIdx.x * 4 + wv;

  __shared__ float sp[8];
  if (tid < 8) sp[tid] = 0.f;
  __syncthreads();

  float acc[8] = {0.f,0.f,0.f,0.f,0.f,0.f,0.f,0.f};
  const float4* x4 = (const float4*)x + (size_t)t * 256;
  u16x4* xb4 = (u16x4*)xb + (size_t)t * 256;
  #pragma unroll
  for (int it = 0; it < 4; ++it) {
    const float4 xv = x4[it * 64 + lane];
    u16x4 bv;
    bv[0] = bf16rne(xv.x); bv[1] = bf16rne(xv.y);
    bv[2] = bf16rne(xv.z); bv[3] = bf16rne(xv.w);
    xb4[it * 64 + lane] = bv;
    const int d0 = (it * 64 + lane) * 4;
    #pragma unroll
    for (int j = 0; j < 4; ++j) {
      const float xs = (j == 0) ? xv.x : ((j == 1) ? xv.y : ((j == 2) ? xv.z : xv.w));
      const float* g = gw + (size_t)(d0 + j) * 8;
      #pragma unroll
      for (int e2 = 0; e2 < 8; ++e2) acc[e2] += xs * g[e2];
    }
  }
  #pragma unroll
  for (int e2 = 0; e2 < 8; ++e2) {
    float v = acc[e2];
    v += __shfl_xor(v, 1);  v += __shfl_xor(v, 2);  v += __shfl_xor(v, 4);
    v += __shfl_xor(v, 8);  v += __shfl_xor(v, 16); v += __shfl_xor(v, 32);
    acc[e2] = v;
  }
  float p[8]; float mx = -1e30f;
  #pragma unroll
  for (int e2 = 0; e2 < 8; ++e2) { p[e2] = acc[e2] + gb[e2]; mx = fmaxf(mx, p[e2]); }
  float s = 0.f;
  #pragma unroll
  for (int e2 = 0; e2 < 8; ++e2) { p[e2] = expf(p[e2] - mx); s += p[e2]; }
  const float inv = 1.f / s;
  #pragma unroll
  for (int e2 = 0; e2 < 8; ++e2) p[e2] *= inv;

  if (lane == 0) {
    int i1 = 0; float v1 = p[0];
    #pragma unroll
    for (int e2 = 1; e2 < 8; ++e2) if (p[e2] > v1) { v1 = p[e2]; i1 = e2; }
    int i2 = 0; float v2 = -1.f;
    #pragma unroll
    for (int e2 = 0; e2 < 8; ++e2) if (e2 != i1 && p[e2] > v2) { v2 = p[e2]; i2 = e2; }
    const float den = v1 + v2 + 1e-6f;
    const int p1 = atomicAdd(&cnt[i1], 1);
    list[i1 * NTOK + p1] = t; pairw[i1 * NTOK + p1] = v1 / den;
    slotE[2 * t] = i1; slotP[2 * t] = p1;
    const int p2 = atomicAdd(&cnt[i2], 1);
    list[i2 * NTOK + p2] = t; pairw[i2 * NTOK + p2] = v2 / den;
    slotE[2 * t + 1] = i2; slotP[2 * t + 1] = p2;
    #pragma unroll
    for (int e2 = 0; e2 < 8; ++e2) atomicAdd(&sp[e2], p[e2]);
  }
  __syncthreads();
  if (tid < 8) atomicAdd(&sump[tid], sp[tid]);
}

// ---------------- fp32 [R][C] -> bf16 [C][R] transpose ----------------
__global__ __launch_bounds__(256) void conv_transpose(
    const float* __restrict__ in, u16* __restrict__ out, int R, int C) {
  __shared__ float tile[64][65];
  const int e = blockIdx.z;
  const float* pin = in + (size_t)e * R * C;
  u16* pout = out + (size_t)e * R * C;
  const int tx = threadIdx.x & 15;
  const int ty = threadIdx.x >> 4;
  const int c0 = blockIdx.x * 64;
  const int r0 = blockIdx.y * 64;
  #pragma unroll
  for (int i = 0; i < 4; ++i) {
    const int r = ty + i * 16;
    const float4 v = *(const float4*)(pin + (size_t)(r0 + r) * C + c0 + tx * 4);
    tile[r][tx * 4 + 0] = v.x;
    tile[r][tx * 4 + 1] = v.y;
    tile[r][tx * 4 + 2] = v.z;
    tile[r][tx * 4 + 3] = v.w;
  }
  __syncthreads();
  #pragma unroll
  for (int i = 0; i < 4; ++i) {
    const int c = ty + i * 16;
    u16x4 o;
    o[0] = bf16rne(tile[tx * 4 + 0][c]);
    o[1] = bf16rne(tile[tx * 4 + 1][c]);
    o[2] = bf16rne(tile[tx * 4 + 2][c]);
    o[3] = bf16rne(tile[tx * 4 + 3][c]);
    *(u16x4*)(pout + (size_t)(c0 + c) * R + r0 + tx * 4) = o;
  }
}

// ---------------- routing finalize: offsets, padding, 128-gran tile table ----------------
__global__ void route_finalize(const int* __restrict__ cnt, const float* __restrict__ sump,
                               int* __restrict__ padc, int* __restrict__ offs,
                               int* __restrict__ list, float* __restrict__ pairw,
                               int* __restrict__ t1e, int* __restrict__ t1r,
                               float* __restrict__ lb_out) {
  __shared__ int s_c[8], s_p[8];
  const int tid = threadIdx.x;
  if (tid == 0) {
    int o = 0; float lb = 0.f;
    for (int e = 0; e < 8; ++e) {
      const int c = cnt[e];
      const int pc = (c + 127) & ~127;
      s_c[e] = c; s_p[e] = pc;
      padc[e] = pc; offs[e] = o; o += pc;
      lb += ((float)c / 8192.f) * (sump[e] / 8192.f);
    }
    lb_out[0] = 0.01f * 8.f * lb;
    int n1 = 0;
    for (int e = 0; e < 8; ++e)
      for (int r = 0; r < s_p[e]; r += 128) { t1e[n1] = e; t1r[n1] = r; ++n1; }
    for (; n1 < NT1; ++n1) { t1e[n1] = -1; t1r[n1] = 0; }
  }
  __syncthreads();
  for (int e = 0; e < 8; ++e)
    for (int pq = s_c[e] + tid; pq < s_p[e]; pq += blockDim.x) {
      list[e * NTOK + pq] = 0; pairw[e * NTOK + pq] = 0.f;
    }
}

// ---------------- GEMM1: 128x256x32, 16x16x32 MFMA (dense reads), fused SwiGLU ----------
// Per-wave 64x128: acc[4][8], aF[4]+bF[8] = 12 reads / 32 MFMA (0.375).
// B rows: 16-row a/g groups: rb>>4 = wc*8+n; col16 = (rb>>4)>>1, isg = (rb>>4)&1.
__global__ __launch_bounds__(256) void gemm1_kernel(
    const u16* __restrict__ xb, const u16* __restrict__ w1t,
    const float* __restrict__ b1, const int* __restrict__ list,
    const int* __restrict__ offs,
    const int* __restrict__ t1e, const int* __restrict__ t1r,
    u16* __restrict__ act) {
  const int tt = blockIdx.y;
  const int e = t1e[tt];
  if (e < 0) return;
  const int row0 = t1r[tt];
  const int j = blockIdx.x;
  const int off_e = offs[e];

  __shared__ u16 lds[24576];  // A: [buf][128][32] @0 (2x4096), B: [buf][256][32] @8192 (2x8192). 48 KiB.

  const int tid = threadIdx.x;
  const int lane = tid & 63;
  const int wv = tid >> 6;
  const int wr = wv >> 1, wc = wv & 1;
  const int l15 = lane & 15, l4 = lane >> 4;

  const int rt = tid >> 2;
  const int ce = ((tid & 3) ^ ((rt >> 1) & 3)) * 8;
  const int tok0 = list[e * NTOK + row0 + rt];
  const int tok1 = list[e * NTOK + row0 + rt + 64];
  const u16* srcA0 = xb + (size_t)tok0 * DDIM + ce;
  const u16* srcA1 = xb + (size_t)tok1 * DDIM + ce;
  const u16* srcB[4];
  #pragma unroll
  for (int seg = 0; seg < 4; ++seg) {
    const int rb = rt + seg * 64;
    const int q = rb >> 4;
    const int gn = j * 128 + (q >> 1) * 16 + (rb & 15) + (q & 1) * FDIM;
    srcB[seg] = w1t + ((size_t)e * 2 * FDIM + gn) * DDIM + ce;
  }

  const int kel = (l4 ^ ((l15 >> 1) & 3)) * 8;
  const int aBase = (wr * 64 + l15) * 32 + kel;    // + m*512 + buf
  const int bBase = (wc * 128 + l15) * 32 + kel;   // + n*512 + buf

  f32x4 acc[4][8];
  #pragma unroll
  for (int m = 0; m < 4; ++m)
    #pragma unroll
    for (int n = 0; n < 8; ++n) { acc[m][n][0]=0.f; acc[m][n][1]=0.f; acc[m][n][2]=0.f; acc[m][n][3]=0.f; }

  #define STAGE1(buf, kt) do { \
    u16* _dA = &lds[(buf) * 4096 + wv * 512]; \
    u16* _dB = &lds[8192 + (buf) * 8192 + wv * 512]; \
    load_lds16(srcA0 + (kt) * 32, _dA); \
    load_lds16(srcA1 + (kt) * 32, _dA + 2048); \
    load_lds16(srcB[0] + (kt) * 32, _dB); \
    load_lds16(srcB[1] + (kt) * 32, _dB + 2048); \
    load_lds16(srcB[2] + (kt) * 32, _dB + 4096); \
    load_lds16(srcB[3] + (kt) * 32, _dB + 6144); \
  } while (0)

  STAGE1(0, 0);
  for (int kt = 0; kt < DDIM / 32; ++kt) {
    const int cur = kt & 1;
    __syncthreads();
    if (kt + 1 < DDIM / 32) STAGE1(cur ^ 1, kt + 1);
    const int bA = cur * 4096;
    const int bB = 8192 + cur * 8192;
    bf16x8 aF[4], bF[8];
    #pragma unroll
    for (int m = 0; m < 4; ++m) aF[m] = *(const bf16x8*)&lds[bA + aBase + m * 512];
    #pragma unroll
    for (int n = 0; n < 8; ++n) bF[n] = *(const bf16x8*)&lds[bB + bBase + n * 512];
    #pragma unroll
    for (int m = 0; m < 4; ++m)
      #pragma unroll
      for (int n = 0; n < 8; ++n)
        acc[m][n] = __builtin_amdgcn_mfma_f32_16x16x32_bf16(aF[m], bF[n], acc[m][n], 0, 0, 0);
  }
  #undef STAGE1

  // epilogue: bias + SwiGLU (sigmoid-form gelu) -> bf16 act
  // acc[m][2p]=a, acc[m][2p+1]=g; col = j*128 + (wc*4+p)*16 + l15
  const size_t actrow0 = (size_t)(off_e + row0);
  #pragma unroll
  for (int p2 = 0; p2 < 4; ++p2) {
    const int col = j * 128 + (wc * 4 + p2) * 16 + l15;
    const float ba = b1[e * (2 * FDIM) + col];
    const float bg = b1[e * (2 * FDIM) + FDIM + col];
    #pragma unroll
    for (int m = 0; m < 4; ++m) {
      #pragma unroll
      for (int jr = 0; jr < 4; ++jr) {
        const int row = wr * 64 + m * 16 + l4 * 4 + jr;
        const float a = acc[m][2 * p2][jr] + ba;
        const float g = acc[m][2 * p2 + 1][jr] + bg;
        const float u2 = 1.5957691216057308f * (g + 0.044715f * g * g * g);
        const float sg = 1.f / (1.f + __expf(-u2));
        act[(actrow0 + row) * FDIM + col] = bf16rne(a * g * sg);
      }
    }
  }
}

// ---------------- GEMM2: 128x128x32, 16x16x32 MFMA (R9 core), bf16 y-stores ----------
// Grid 1152: r8=bid&7 (XCD), q=bid>>3, jt=q&7, tt=(q>>3)*8+r8.
__global__ __launch_bounds__(256) void gemm2_kernel(
    const u16* __restrict__ act, const u16* __restrict__ w2t,
    const float* __restrict__ b2, const float* __restrict__ pairw,
    const int* __restrict__ offs,
    const int* __restrict__ t1e, const int* __restrict__ t1r,
    u16* __restrict__ y) {
  const int bid = blockIdx.x;
  const int r8 = bid & 7;
  const int q = bid >> 3;
  const int jt = q & 7;
  const int tt = (q >> 3) * 8 + r8;
  const int e = t1e[tt];
  if (e < 0) return;
  const int row0 = t1r[tt];
  const int off_e = offs[e];

  __shared__ u16 lds[16384];

  const int tid = threadIdx.x;
  const int lane = tid & 63;
  const int wv = tid >> 6;
  const int wr = wv >> 1, wc = wv & 1;
  const int l15 = lane & 15, l4 = lane >> 4;

  const int rt = tid >> 2;
  const int ce = ((tid & 3) ^ ((rt >> 1) & 3)) * 8;
  const u16* srcA0 = act + (size_t)(off_e + row0 + rt) * FDIM + ce;
  const u16* srcA1 = act + (size_t)(off_e + row0 + rt + 64) * FDIM + ce;
  const u16* srcB0 = w2t + ((size_t)e * DDIM + jt * 128 + rt) * FDIM + ce;
  const u16* srcB1 = w2t + ((size_t)e * DDIM + jt * 128 + rt + 64) * FDIM + ce;

  const int kel = (l4 ^ ((l15 >> 1) & 3)) * 8;
  const int aBase = (wr * 64 + l15) * 32 + kel;
  const int bBase = (wc * 64 + l15) * 32 + kel;

  f32x4 acc[4][4];
  #pragma unroll
  for (int m = 0; m < 4; ++m)
    #pragma unroll
    for (int n = 0; n < 4; ++n) { acc[m][n][0]=0.f; acc[m][n][1]=0.f; acc[m][n][2]=0.f; acc[m][n][3]=0.f; }

  #define STAGE2(buf, kt) do { \
    u16* _dA = &lds[(buf) * 4096 + wv * 512]; \
    u16* _dB = &lds[8192 + (buf) * 4096 + wv * 512]; \
    load_lds16(srcA0 + (kt) * 32, _dA); \
    load_lds16(srcA1 + (kt) * 32, _dA + 2048); \
    load_lds16(srcB0 + (kt) * 32, _dB); \
    load_lds16(srcB1 + (kt) * 32, _dB + 2048); \
  } while (0)

  STAGE2(0, 0);
  for (int kt = 0; kt < FDIM / 32; ++kt) {
    const int cur = kt & 1;
    __syncthreads();
    if (kt + 1 < FDIM / 32) STAGE2(cur ^ 1, kt + 1);
    const int bA = cur * 4096;
    const int bB = 8192 + cur * 4096;
    bf16x8 aF[4], bF[4];
    #pragma unroll
    for (int m = 0; m < 4; ++m) aF[m] = *(const bf16x8*)&lds[bA + aBase + m * 512];
    #pragma unroll
    for (int n = 0; n < 4; ++n) bF[n] = *(const bf16x8*)&lds[bB + bBase + n * 512];
    #pragma unroll
    for (int m = 0; m < 4; ++m)
      #pragma unroll
      for (int n = 0; n < 4; ++n)
        acc[m][n] = __builtin_amdgcn_mfma_f32_16x16x32_bf16(aF[m], bF[n], acc[m][n], 0, 0, 0);
  }
  #undef STAGE2

  // epilogue: y = bf16((acc + b2) * pw), plain coalesced stores
  #pragma unroll
  for (int m = 0; m < 4; ++m) {
    #pragma unroll
    for (int jr = 0; jr < 4; ++jr) {
      const int row = wr * 64 + m * 16 + l4 * 4 + jr;
      const int pos = row0 + row;
      const float pw = pairw[e * NTOK + pos];
      if (pw != 0.f) {
        u16* yr = y + (size_t)(off_e + pos) * DDIM;
        #pragma unroll
        for (int n = 0; n < 4; ++n) {
          const int col = jt * 128 + wc * 64 + n * 16 + l15;
          yr[col] = bf16rne((acc[m][n][jr] + b2[e * DDIM + col]) * pw);
        }
      }
    }
  }
}

// ---------------- gather: out[t] = y[slot1(t)] + y[slot2(t)]  (bf16 -> f32) ----------------
__global__ __launch_bounds__(256) void gather_kernel(
    const u16* __restrict__ y, const int* __restrict__ slotE,
    const int* __restrict__ slotP, const int* __restrict__ offs,
    float* __restrict__ out) {
  const int t = blockIdx.x * 4 + (threadIdx.x >> 6);
  const int lane = threadIdx.x & 63;
  const int r1 = offs[slotE[2 * t]] + slotP[2 * t];
  const int r2 = offs[slotE[2 * t + 1]] + slotP[2 * t + 1];
  const u16x8* y1 = (const u16x8*)(y + (size_t)r1 * DDIM);
  const u16x8* y2 = (const u16x8*)(y + (size_t)r2 * DDIM);
  float4* o4 = (float4*)(out + (size_t)t * DDIM);
  #pragma unroll
  for (int i = 0; i < 2; ++i) {
    const u16x8 a = y1[i * 64 + lane];
    const u16x8 b = y2[i * 64 + lane];
    float4 r0, r1f;
    r0.x = bf16tof(a[0]) + bf16tof(b[0]);
    r0.y = bf16tof(a[1]) + bf16tof(b[1]);
    r0.z = bf16tof(a[2]) + bf16tof(b[2]);
    r0.w = bf16tof(a[3]) + bf16tof(b[3]);
    r1f.x = bf16tof(a[4]) + bf16tof(b[4]);
    r1f.y = bf16tof(a[5]) + bf16tof(b[5]);
    r1f.z = bf16tof(a[6]) + bf16tof(b[6]);
    r1f.w = bf16tof(a[7]) + bf16tof(b[7]);
    o4[(i * 64 + lane) * 2]     = r0;
    o4[(i * 64 + lane) * 2 + 1] = r1f;
  }
}

extern "C" void kernel_launch(void* const* d_in, const int* in_sizes, int n_in,
                              void* d_out, int out_size, void* d_ws, size_t ws_size,
                              hipStream_t stream) {
  const float* x   = (const float*)d_in[0];
  const float* gw  = (const float*)d_in[1];
  const float* gb  = (const float*)d_in[2];
  const float* f1w = (const float*)d_in[3];
  const float* f1b = (const float*)d_in[4];
  const float* f2w = (const float*)d_in[5];
  const float* f2b = (const float*)d_in[6];
  float* out = (float*)d_out;
  char* ws = (char*)d_ws;

  u16*   xb    = (u16*)(ws + WS_XB);
  u16*   w1t   = (u16*)(ws + WS_W1T);
  u16*   y     = (u16*)(ws + WS_W1T);    // reuses w1t region after gemm1
  u16*   w2t   = (u16*)(ws + WS_W2T);
  u16*   act   = (u16*)(ws + WS_ACT);
  int*   list  = (int*)(ws + WS_LIST);
  float* pairw = (float*)(ws + WS_PAIRW);
  int*   cnt   = (int*)(ws + WS_CNT);
  float* sump  = (float*)(ws + WS_SUMP);
  int*   padc  = (int*)(ws + WS_PAD);
  int*   offs  = (int*)(ws + WS_OFF);
  int*   t1e   = (int*)(ws + WS_T1E);
  int*   t1r   = (int*)(ws + WS_T1R);
  int*   slotE = (int*)(ws + WS_SE);
  int*   slotP = (int*)(ws + WS_SP);

  (void)hipMemsetAsync(ws + WS_CNT, 0, 64, stream);  // cnt + sump

  gate_kernel<<<NTOK / 4, 256, 0, stream>>>(x, gw, gb, xb, cnt, sump, list, pairw, slotE, slotP);
  conv_transpose<<<dim3(8192 / 64, 1024 / 64, 8), 256, 0, stream>>>(f1w, w1t, 1024, 8192);
  conv_transpose<<<dim3(1024 / 64, 4096 / 64, 8), 256, 0, stream>>>(f2w, w2t, 4096, 1024);
  route_finalize<<<1, 256, 0, stream>>>(cnt, sump, padc, offs, list, pairw,
                                        t1e, t1r, out + 8388608);
  gemm1_kernel<<<dim3(32, NT1), 256, 0, stream>>>(xb, w1t, f1b, list, offs, t1e, t1r, act);
  gemm2_kernel<<<NT1 * 8, 256, 0, stream>>>(act, w2t, f2b, pairw, offs, t1e, t1r, y);
  gather_kernel<<<NTOK / 4, 256, 0, stream>>>(y, slotE, slotP, offs, out);
}

// Round 23
// 922.494 us; speedup vs baseline: 1.0400x; 1.0400x over previous
//
#include <hip/hip_runtime.h>
#include <hip/hip_bf16.h>
#include <stdint.h>

typedef __attribute__((ext_vector_type(4))) float f32x4;
typedef __attribute__((ext_vector_type(16))) float f32x16;
typedef __attribute__((ext_vector_type(8))) __bf16 bf16x8;
typedef __attribute__((ext_vector_type(4))) unsigned short u16x4;
typedef __attribute__((ext_vector_type(8))) unsigned short u16x8;
typedef unsigned short u16;

#define NTOK 8192
#define DDIM 1024
#define FDIM 4096
#define NEXP 8
#define NT1 144

// ---- workspace layout (bytes) ----
#define WS_XB    0ull
#define WS_W1T   (16777216ull)                 // w1t for gemm1; REUSED as y[rows][1024] bf16 by gemm2
#define WS_W2T   (WS_W1T + 134217728ull)
#define WS_ACT   (WS_W2T + 67108864ull)
#define WS_LIST  (WS_ACT + 142606336ull)
#define WS_PAIRW (WS_LIST + 262144ull)
#define WS_CNT   (WS_PAIRW + 262144ull)
#define WS_SUMP  (WS_CNT + 32ull)
#define WS_PAD   (WS_SUMP + 32ull)
#define WS_OFF   (WS_PAD + 32ull)
#define WS_T1E   (WS_OFF + 32ull)              // 144 int (1 KiB reserved)
#define WS_T1R   (WS_T1E + 1024ull)            // 144 int (1 KiB reserved)
#define WS_SE    (WS_T1R + 1024ull)            // 8192*2 int
#define WS_SP    (WS_SE + 65536ull)            // 8192*2 int

static __device__ __forceinline__ u16 bf16rne(float f) {
  union { float f; uint32_t u; } c; c.f = f;
  return (u16)((c.u + 0x7FFFu + ((c.u >> 16) & 1u)) >> 16);
}

static __device__ __forceinline__ float bf16tof(u16 v) {
  union { uint32_t u; float f; } c; c.u = ((uint32_t)v) << 16;
  return c.f;
}

static __device__ __forceinline__ void load_lds16(const void* g, void* l) {
  __builtin_amdgcn_global_load_lds((const __attribute__((address_space(1))) void*)g,
                                   (__attribute__((address_space(3))) void*)l, 16, 0, 0);
}

// ---------------- gating + routing + x->bf16 ----------------
__global__ __launch_bounds__(256) void gate_kernel(
    const float* __restrict__ x, const float* __restrict__ gw,
    const float* __restrict__ gb, u16* __restrict__ xb,
    int* __restrict__ cnt, float* __restrict__ sump,
    int* __restrict__ list, float* __restrict__ pairw,
    int* __restrict__ slotE, int* __restrict__ slotP) {
  const int tid = threadIdx.x;
  const int lane = tid & 63;
  const int wv = tid >> 6;
  const int t = blockIdx.x * 4 + wv;

  __shared__ float sp[8];
  if (tid < 8) sp[tid] = 0.f;
  __syncthreads();

  float acc[8] = {0.f,0.f,0.f,0.f,0.f,0.f,0.f,0.f};
  const float4* x4 = (const float4*)x + (size_t)t * 256;
  u16x4* xb4 = (u16x4*)xb + (size_t)t * 256;
  #pragma unroll
  for (int it = 0; it < 4; ++it) {
    const float4 xv = x4[it * 64 + lane];
    u16x4 bv;
    bv[0] = bf16rne(xv.x); bv[1] = bf16rne(xv.y);
    bv[2] = bf16rne(xv.z); bv[3] = bf16rne(xv.w);
    xb4[it * 64 + lane] = bv;
    const int d0 = (it * 64 + lane) * 4;
    #pragma unroll
    for (int j = 0; j < 4; ++j) {
      const float xs = (j == 0) ? xv.x : ((j == 1) ? xv.y : ((j == 2) ? xv.z : xv.w));
      const float* g = gw + (size_t)(d0 + j) * 8;
      #pragma unroll
      for (int e2 = 0; e2 < 8; ++e2) acc[e2] += xs * g[e2];
    }
  }
  #pragma unroll
  for (int e2 = 0; e2 < 8; ++e2) {
    float v = acc[e2];
    v += __shfl_xor(v, 1);  v += __shfl_xor(v, 2);  v += __shfl_xor(v, 4);
    v += __shfl_xor(v, 8);  v += __shfl_xor(v, 16); v += __shfl_xor(v, 32);
    acc[e2] = v;
  }
  float p[8]; float mx = -1e30f;
  #pragma unroll
  for (int e2 = 0; e2 < 8; ++e2) { p[e2] = acc[e2] + gb[e2]; mx = fmaxf(mx, p[e2]); }
  float s = 0.f;
  #pragma unroll
  for (int e2 = 0; e2 < 8; ++e2) { p[e2] = expf(p[e2] - mx); s += p[e2]; }
  const float inv = 1.f / s;
  #pragma unroll
  for (int e2 = 0; e2 < 8; ++e2) p[e2] *= inv;

  if (lane == 0) {
    int i1 = 0; float v1 = p[0];
    #pragma unroll
    for (int e2 = 1; e2 < 8; ++e2) if (p[e2] > v1) { v1 = p[e2]; i1 = e2; }
    int i2 = 0; float v2 = -1.f;
    #pragma unroll
    for (int e2 = 0; e2 < 8; ++e2) if (e2 != i1 && p[e2] > v2) { v2 = p[e2]; i2 = e2; }
    const float den = v1 + v2 + 1e-6f;
    const int p1 = atomicAdd(&cnt[i1], 1);
    list[i1 * NTOK + p1] = t; pairw[i1 * NTOK + p1] = v1 / den;
    slotE[2 * t] = i1; slotP[2 * t] = p1;
    const int p2 = atomicAdd(&cnt[i2], 1);
    list[i2 * NTOK + p2] = t; pairw[i2 * NTOK + p2] = v2 / den;
    slotE[2 * t + 1] = i2; slotP[2 * t + 1] = p2;
    #pragma unroll
    for (int e2 = 0; e2 < 8; ++e2) atomicAdd(&sp[e2], p[e2]);
  }
  __syncthreads();
  if (tid < 8) atomicAdd(&sump[tid], sp[tid]);
}

// ---------------- fp32 [R][C] -> bf16 [C][R] transpose ----------------
__global__ __launch_bounds__(256) void conv_transpose(
    const float* __restrict__ in, u16* __restrict__ out, int R, int C) {
  __shared__ float tile[64][65];
  const int e = blockIdx.z;
  const float* pin = in + (size_t)e * R * C;
  u16* pout = out + (size_t)e * R * C;
  const int tx = threadIdx.x & 15;
  const int ty = threadIdx.x >> 4;
  const int c0 = blockIdx.x * 64;
  const int r0 = blockIdx.y * 64;
  #pragma unroll
  for (int i = 0; i < 4; ++i) {
    const int r = ty + i * 16;
    const float4 v = *(const float4*)(pin + (size_t)(r0 + r) * C + c0 + tx * 4);
    tile[r][tx * 4 + 0] = v.x;
    tile[r][tx * 4 + 1] = v.y;
    tile[r][tx * 4 + 2] = v.z;
    tile[r][tx * 4 + 3] = v.w;
  }
  __syncthreads();
  #pragma unroll
  for (int i = 0; i < 4; ++i) {
    const int c = ty + i * 16;
    u16x4 o;
    o[0] = bf16rne(tile[tx * 4 + 0][c]);
    o[1] = bf16rne(tile[tx * 4 + 1][c]);
    o[2] = bf16rne(tile[tx * 4 + 2][c]);
    o[3] = bf16rne(tile[tx * 4 + 3][c]);
    *(u16x4*)(pout + (size_t)(c0 + c) * R + r0 + tx * 4) = o;
  }
}

// ---------------- routing finalize: offsets, padding, 128-gran tile table ----------------
__global__ void route_finalize(const int* __restrict__ cnt, const float* __restrict__ sump,
                               int* __restrict__ padc, int* __restrict__ offs,
                               int* __restrict__ list, float* __restrict__ pairw,
                               int* __restrict__ t1e, int* __restrict__ t1r,
                               float* __restrict__ lb_out) {
  __shared__ int s_c[8], s_p[8];
  const int tid = threadIdx.x;
  if (tid == 0) {
    int o = 0; float lb = 0.f;
    for (int e = 0; e < 8; ++e) {
      const int c = cnt[e];
      const int pc = (c + 127) & ~127;
      s_c[e] = c; s_p[e] = pc;
      padc[e] = pc; offs[e] = o; o += pc;
      lb += ((float)c / 8192.f) * (sump[e] / 8192.f);
    }
    lb_out[0] = 0.01f * 8.f * lb;
    int n1 = 0;
    for (int e = 0; e < 8; ++e)
      for (int r = 0; r < s_p[e]; r += 128) { t1e[n1] = e; t1r[n1] = r; ++n1; }
    for (; n1 < NT1; ++n1) { t1e[n1] = -1; t1r[n1] = 0; }
  }
  __syncthreads();
  for (int e = 0; e < 8; ++e)
    for (int pq = s_c[e] + tid; pq < s_p[e]; pq += blockDim.x) {
      list[e * NTOK + pq] = 0; pairw[e * NTOK + pq] = 0.f;
    }
}

// ---------------- GEMM1: 128x256x32, 32x32x16 MFMA, fused SwiGLU (R15/R21) ----------------
__global__ __launch_bounds__(256) void gemm1_kernel(
    const u16* __restrict__ xb, const u16* __restrict__ w1t,
    const float* __restrict__ b1, const int* __restrict__ list,
    const int* __restrict__ offs,
    const int* __restrict__ t1e, const int* __restrict__ t1r,
    u16* __restrict__ act) {
  const int tt = blockIdx.y;
  const int e = t1e[tt];
  if (e < 0) return;
  const int row0 = t1r[tt];
  const int j = blockIdx.x;
  const int off_e = offs[e];

  __shared__ u16 lds[24576];  // A: [buf][128][32] @0 (2x4096), B: [buf][256][32] @8192 (2x8192). 48 KiB.

  const int tid = threadIdx.x;
  const int lane = tid & 63;
  const int wv = tid >> 6;
  const int wr = wv >> 1, wc = wv & 1;
  const int l31 = lane & 31, s5 = lane >> 5;

  const int rt = tid >> 2;
  const int ce = ((tid & 3) ^ ((rt >> 1) & 3)) * 8;
  const int tok0 = list[e * NTOK + row0 + rt];
  const int tok1 = list[e * NTOK + row0 + rt + 64];
  const u16* srcA0 = xb + (size_t)tok0 * DDIM + ce;
  const u16* srcA1 = xb + (size_t)tok1 * DDIM + ce;
  const u16* srcB[4];
  #pragma unroll
  for (int seg = 0; seg < 4; ++seg) {
    const int rb = rt + seg * 64;
    const int q = rb >> 5;
    const int gn = j * 128 + (q >> 1) * 32 + (rb & 31) + (q & 1) * FDIM;
    srcB[seg] = w1t + ((size_t)e * 2 * FDIM + gn) * DDIM + ce;
  }

  const int xsw = (l31 >> 1) & 3;
  const int kel0 = (s5 ^ xsw) * 8;
  const int aB0 = (wr * 64 + l31) * 32 + kel0;   const int aB1 = aB0 ^ 16;
  const int bB0 = (wc * 128 + l31) * 32 + kel0;  const int bB1 = bB0 ^ 16;

  f32x16 acc[2][4];
  #pragma unroll
  for (int m = 0; m < 2; ++m)
    #pragma unroll
    for (int n = 0; n < 4; ++n)
      #pragma unroll
      for (int i = 0; i < 16; ++i) acc[m][n][i] = 0.f;

  #define STAGE1(buf, kt) do { \
    u16* _dA = &lds[(buf) * 4096 + wv * 512]; \
    u16* _dB = &lds[8192 + (buf) * 8192 + wv * 512]; \
    load_lds16(srcA0 + (kt) * 32, _dA); \
    load_lds16(srcA1 + (kt) * 32, _dA + 2048); \
    load_lds16(srcB[0] + (kt) * 32, _dB); \
    load_lds16(srcB[1] + (kt) * 32, _dB + 2048); \
    load_lds16(srcB[2] + (kt) * 32, _dB + 4096); \
    load_lds16(srcB[3] + (kt) * 32, _dB + 6144); \
  } while (0)

  STAGE1(0, 0);
  for (int kt = 0; kt < DDIM / 32; ++kt) {
    const int cur = kt & 1;
    __syncthreads();
    if (kt + 1 < DDIM / 32) STAGE1(cur ^ 1, kt + 1);
    const int bA = cur * 4096;
    const int bB = 8192 + cur * 8192;
    bf16x8 a0[2], a1[2], Bh0[4], Bh1[4];
    #pragma unroll
    for (int m = 0; m < 2; ++m) {
      a0[m] = *(const bf16x8*)&lds[bA + aB0 + m * 1024];
      a1[m] = *(const bf16x8*)&lds[bA + aB1 + m * 1024];
    }
    #pragma unroll
    for (int n = 0; n < 4; ++n) {
      Bh0[n] = *(const bf16x8*)&lds[bB + bB0 + n * 1024];
      Bh1[n] = *(const bf16x8*)&lds[bB + bB1 + n * 1024];
    }
    #pragma unroll
    for (int m = 0; m < 2; ++m)
      #pragma unroll
      for (int n = 0; n < 4; ++n) {
        acc[m][n] = __builtin_amdgcn_mfma_f32_32x32x16_bf16(a0[m], Bh0[n], acc[m][n], 0, 0, 0);
        acc[m][n] = __builtin_amdgcn_mfma_f32_32x32x16_bf16(a1[m], Bh1[n], acc[m][n], 0, 0, 0);
      }
  }
  #undef STAGE1

  // epilogue: bias + SwiGLU (sigmoid-form gelu) -> bf16 act
  const size_t actrow0 = (size_t)(off_e + row0);
  #pragma unroll
  for (int p2 = 0; p2 < 2; ++p2) {
    const int col = j * 128 + wc * 64 + p2 * 32 + l31;
    const float ba = b1[e * (2 * FDIM) + col];
    const float bg = b1[e * (2 * FDIM) + FDIM + col];
    #pragma unroll
    for (int m = 0; m < 2; ++m) {
      #pragma unroll
      for (int r = 0; r < 16; ++r) {
        const int row = wr * 64 + m * 32 + (r & 3) + 8 * (r >> 2) + 4 * s5;
        const float a = acc[m][2 * p2][r] + ba;
        const float g = acc[m][2 * p2 + 1][r] + bg;
        const float u2 = 1.5957691216057308f * (g + 0.044715f * g * g * g);
        const float sg = 1.f / (1.f + __expf(-u2));
        act[(actrow0 + row) * FDIM + col] = bf16rne(a * g * sg);
      }
    }
  }
}

// ---------------- GEMM2: 128x128x32 (R13/R15 core), bf16 y-stores (no atomics) ----------
// Grid 1152: r8=bid&7 (XCD), q=bid>>3, jt=q&7, tt=(q>>3)*8+r8.
__global__ __launch_bounds__(256) void gemm2_kernel(
    const u16* __restrict__ act, const u16* __restrict__ w2t,
    const float* __restrict__ b2, const float* __restrict__ pairw,
    const int* __restrict__ offs,
    const int* __restrict__ t1e, const int* __restrict__ t1r,
    u16* __restrict__ y) {
  const int bid = blockIdx.x;
  const int r8 = bid & 7;
  const int q = bid >> 3;
  const int jt = q & 7;
  const int tt = (q >> 3) * 8 + r8;
  const int e = t1e[tt];
  if (e < 0) return;
  const int row0 = t1r[tt];
  const int off_e = offs[e];

  __shared__ u16 lds[16384];

  const int tid = threadIdx.x;
  const int lane = tid & 63;
  const int wv = tid >> 6;
  const int wr = wv >> 1, wc = wv & 1;
  const int l31 = lane & 31, s5 = lane >> 5;

  const int rt = tid >> 2;
  const int ce = ((tid & 3) ^ ((rt >> 1) & 3)) * 8;
  const u16* srcA0 = act + (size_t)(off_e + row0 + rt) * FDIM + ce;
  const u16* srcA1 = act + (size_t)(off_e + row0 + rt + 64) * FDIM + ce;
  const u16* srcB0 = w2t + ((size_t)e * DDIM + jt * 128 + rt) * FDIM + ce;
  const u16* srcB1 = w2t + ((size_t)e * DDIM + jt * 128 + rt + 64) * FDIM + ce;

  const int xsw = (l31 >> 1) & 3;
  const int kel0 = (s5 ^ xsw) * 8;
  const int aB0 = (wr * 64 + l31) * 32 + kel0;  const int aB1 = aB0 ^ 16;
  const int bB0 = (wc * 64 + l31) * 32 + kel0;  const int bB1 = bB0 ^ 16;

  f32x16 acc[2][2];
  #pragma unroll
  for (int m = 0; m < 2; ++m)
    #pragma unroll
    for (int n = 0; n < 2; ++n)
      #pragma unroll
      for (int i = 0; i < 16; ++i) acc[m][n][i] = 0.f;

  #define STAGE2(buf, kt) do { \
    u16* _dA = &lds[(buf) * 4096 + wv * 512]; \
    u16* _dB = &lds[8192 + (buf) * 4096 + wv * 512]; \
    load_lds16(srcA0 + (kt) * 32, _dA); \
    load_lds16(srcA1 + (kt) * 32, _dA + 2048); \
    load_lds16(srcB0 + (kt) * 32, _dB); \
    load_lds16(srcB1 + (kt) * 32, _dB + 2048); \
  } while (0)

  STAGE2(0, 0);
  for (int kt = 0; kt < FDIM / 32; ++kt) {
    const int cur = kt & 1;
    __syncthreads();
    if (kt + 1 < FDIM / 32) STAGE2(cur ^ 1, kt + 1);
    const int bA = cur * 4096;
    const int bB = 8192 + cur * 4096;
    bf16x8 a0[2], a1[2], Bh0[2], Bh1[2];
    #pragma unroll
    for (int m = 0; m < 2; ++m) {
      a0[m] = *(const bf16x8*)&lds[bA + aB0 + m * 1024];
      a1[m] = *(const bf16x8*)&lds[bA + aB1 + m * 1024];
    }
    #pragma unroll
    for (int n = 0; n < 2; ++n) {
      Bh0[n] = *(const bf16x8*)&lds[bB + bB0 + n * 1024];
      Bh1[n] = *(const bf16x8*)&lds[bB + bB1 + n * 1024];
    }
    #pragma unroll
    for (int m = 0; m < 2; ++m)
      #pragma unroll
      for (int n = 0; n < 2; ++n) {
        acc[m][n] = __builtin_amdgcn_mfma_f32_32x32x16_bf16(a0[m], Bh0[n], acc[m][n], 0, 0, 0);
        acc[m][n] = __builtin_amdgcn_mfma_f32_32x32x16_bf16(a1[m], Bh1[n], acc[m][n], 0, 0, 0);
      }
  }
  #undef STAGE2

  // epilogue: y = bf16((acc + b2) * pw), plain coalesced stores (no atomics)
  #pragma unroll
  for (int m = 0; m < 2; ++m) {
    #pragma unroll
    for (int r = 0; r < 16; ++r) {
      const int row = wr * 64 + m * 32 + (r & 3) + 8 * (r >> 2) + 4 * s5;
      const int pos = row0 + row;
      const float pw = pairw[e * NTOK + pos];
      if (pw != 0.f) {
        u16* yr = y + (size_t)(off_e + pos) * DDIM;
        #pragma unroll
        for (int n = 0; n < 2; ++n) {
          const int col = jt * 128 + wc * 64 + n * 32 + l31;
          yr[col] = bf16rne((acc[m][n][r] + b2[e * DDIM + col]) * pw);
        }
      }
    }
  }
}

// ---------------- gather: out[t] = y[slot1(t)] + y[slot2(t)]  (bf16 -> f32) ----------------
__global__ __launch_bounds__(256) void gather_kernel(
    const u16* __restrict__ y, const int* __restrict__ slotE,
    const int* __restrict__ slotP, const int* __restrict__ offs,
    float* __restrict__ out) {
  const int t = blockIdx.x * 4 + (threadIdx.x >> 6);
  const int lane = threadIdx.x & 63;
  const int r1 = offs[slotE[2 * t]] + slotP[2 * t];
  const int r2 = offs[slotE[2 * t + 1]] + slotP[2 * t + 1];
  const u16x8* y1 = (const u16x8*)(y + (size_t)r1 * DDIM);
  const u16x8* y2 = (const u16x8*)(y + (size_t)r2 * DDIM);
  float4* o4 = (float4*)(out + (size_t)t * DDIM);
  #pragma unroll
  for (int i = 0; i < 2; ++i) {
    const u16x8 a = y1[i * 64 + lane];
    const u16x8 b = y2[i * 64 + lane];
    float4 r0, r1f;
    r0.x = bf16tof(a[0]) + bf16tof(b[0]);
    r0.y = bf16tof(a[1]) + bf16tof(b[1]);
    r0.z = bf16tof(a[2]) + bf16tof(b[2]);
    r0.w = bf16tof(a[3]) + bf16tof(b[3]);
    r1f.x = bf16tof(a[4]) + bf16tof(b[4]);
    r1f.y = bf16tof(a[5]) + bf16tof(b[5]);
    r1f.z = bf16tof(a[6]) + bf16tof(b[6]);
    r1f.w = bf16tof(a[7]) + bf16tof(b[7]);
    o4[(i * 64 + lane) * 2]     = r0;
    o4[(i * 64 + lane) * 2 + 1] = r1f;
  }
}

extern "C" void kernel_launch(void* const* d_in, const int* in_sizes, int n_in,
                              void* d_out, int out_size, void* d_ws, size_t ws_size,
                              hipStream_t stream) {
  const float* x   = (const float*)d_in[0];
  const float* gw  = (const float*)d_in[1];
  const float* gb  = (const float*)d_in[2];
  const float* f1w = (const float*)d_in[3];
  const float* f1b = (const float*)d_in[4];
  const float* f2w = (const float*)d_in[5];
  const float* f2b = (const float*)d_in[6];
  float* out = (float*)d_out;
  char* ws = (char*)d_ws;

  u16*   xb    = (u16*)(ws + WS_XB);
  u16*   w1t   = (u16*)(ws + WS_W1T);
  u16*   y     = (u16*)(ws + WS_W1T);    // reuses w1t region after gemm1
  u16*   w2t   = (u16*)(ws + WS_W2T);
  u16*   act   = (u16*)(ws + WS_ACT);
  int*   list  = (int*)(ws + WS_LIST);
  float* pairw = (float*)(ws + WS_PAIRW);
  int*   cnt   = (int*)(ws + WS_CNT);
  float* sump  = (float*)(ws + WS_SUMP);
  int*   padc  = (int*)(ws + WS_PAD);
  int*   offs  = (int*)(ws + WS_OFF);
  int*   t1e   = (int*)(ws + WS_T1E);
  int*   t1r   = (int*)(ws + WS_T1R);
  int*   slotE = (int*)(ws + WS_SE);
  int*   slotP = (int*)(ws + WS_SP);

  (void)hipMemsetAsync(ws + WS_CNT, 0, 64, stream);  // cnt + sump

  gate_kernel<<<NTOK / 4, 256, 0, stream>>>(x, gw, gb, xb, cnt, sump, list, pairw, slotE, slotP);
  conv_transpose<<<dim3(8192 / 64, 1024 / 64, 8), 256, 0, stream>>>(f1w, w1t, 1024, 8192);
  conv_transpose<<<dim3(1024 / 64, 4096 / 64, 8), 256, 0, stream>>>(f2w, w2t, 4096, 1024);
  route_finalize<<<1, 256, 0, stream>>>(cnt, sump, padc, offs, list, pairw,
                                        t1e, t1r, out + 8388608);
  gemm1_kernel<<<dim3(32, NT1), 256, 0, stream>>>(xb, w1t, f1b, list, offs, t1e, t1r, act);
  gemm2_kernel<<<NT1 * 8, 256, 0, stream>>>(act, w2t, f2b, pairw, offs, t1e, t1r, y);
  gather_kernel<<<NTOK / 4, 256, 0, stream>>>(y, slotE, slotP, offs, out);
}